// Round 5
// baseline (191.415 us; speedup 1.0000x reference)
//
#include <hip/hip_runtime.h>
#include <hip/hip_bf16.h>

#define L_SEQ 1024
#define DI    5120
#define DS    16
#define DR    160
#define NE    192      // DR + 2*DS
#define NC    16       // scan chunks
#define CL    64       // chunk length = L_SEQ/NC
#define SPLITK 8
#define KSPLIT (DI / SPLITK)   // 640

// workspace layout (bytes)
#define OFF_P     0
#define SZ_P      (SPLITK * L_SEQ * NE * 4)   // 6,291,456
#define OFF_XDBL  (OFF_P + SZ_P)
#define SZ_XDBL   (L_SEQ * NE * 4)            // 786,432
#define OFF_DELTA (OFF_XDBL + SZ_XDBL)
#define SZ_DELTA  (L_SEQ * DI * 4)            // 20,971,520
#define OFF_HEND  (OFF_DELTA + SZ_DELTA)
#define SZ_H      (NC * DS * DI * 4)          // 5,242,880
#define OFF_APROD (OFF_HEND + SZ_H)
// total ~38.5 MB

// ---------------- GEMM1: x_dbl[l,e] = sum_d x[l,d] * xw[e,d], split-K partials
__global__ __launch_bounds__(256) void k_xdbl(const float* __restrict__ x,
                                              const float* __restrict__ xw,
                                              float* __restrict__ part) {
  __shared__ __align__(16) float sx[64][68];
  __shared__ __align__(16) float sw[64][68];
  const int tid = threadIdx.x;
  const int e0 = blockIdx.x * 64;
  const int l0 = blockIdx.y * 64;
  const int kbase = blockIdx.z * KSPLIT;
  const int te = tid & 15;   // e varies fastest across lanes (coalesced writes)
  const int tl = tid >> 4;
  float acc[4][4];
#pragma unroll
  for (int i = 0; i < 4; ++i)
#pragma unroll
    for (int j = 0; j < 4; ++j) acc[i][j] = 0.f;

  const int sr = tid >> 4;          // staging row base 0..15
  const int sc = (tid & 15) << 2;   // staging col 0..60

  for (int k0 = 0; k0 < KSPLIT; k0 += 64) {
#pragma unroll
    for (int it = 0; it < 4; ++it) {
      int r = sr + it * 16;
      float4 v = *(const float4*)&x[(size_t)(l0 + r) * DI + kbase + k0 + sc];
      *(float4*)&sx[r][sc] = v;
      float4 w = *(const float4*)&xw[(size_t)(e0 + r) * DI + kbase + k0 + sc];
      *(float4*)&sw[r][sc] = w;
    }
    __syncthreads();
#pragma unroll 4
    for (int k4 = 0; k4 < 64; k4 += 4) {
      float a[4][4], b[4][4];
#pragma unroll
      for (int i = 0; i < 4; ++i)
        *(float4*)&a[i][0] = *(const float4*)&sx[tl + 16 * i][k4];
#pragma unroll
      for (int j = 0; j < 4; ++j)
        *(float4*)&b[j][0] = *(const float4*)&sw[te + 16 * j][k4];
#pragma unroll
      for (int i = 0; i < 4; ++i)
#pragma unroll
        for (int j = 0; j < 4; ++j)
#pragma unroll
          for (int q = 0; q < 4; ++q)
            acc[i][j] += a[i][q] * b[j][q];
    }
    __syncthreads();
  }
#pragma unroll
  for (int i = 0; i < 4; ++i)
#pragma unroll
    for (int j = 0; j < 4; ++j) {
      int l = l0 + tl + 16 * i;
      int e = e0 + te + 16 * j;
      part[((size_t)blockIdx.z * L_SEQ + l) * NE + e] = acc[i][j];
    }
}

__global__ __launch_bounds__(256) void k_xdbl_reduce(const float* __restrict__ part,
                                                     float* __restrict__ xdbl) {
  int i = blockIdx.x * 256 + threadIdx.x;   // 196608 total, grid=768
  float s = 0.f;
#pragma unroll
  for (int z = 0; z < SPLITK; ++z) s += part[(size_t)z * L_SEQ * NE + i];
  xdbl[i] = s;
}

// ---------------- GEMM2: delta[l,d] = softplus(sum_r dt[l,r]*dtw[d,r] + b[d])
__global__ __launch_bounds__(256) void k_delta(const float* __restrict__ xdbl,
                                               const float* __restrict__ dtw,
                                               const float* __restrict__ dtb,
                                               float* __restrict__ delta) {
  __shared__ __align__(16) float sdt[32][164];
  __shared__ __align__(16) float sw[64][164];
  const int tid = threadIdx.x;
  const int d0 = blockIdx.x * 64;
  const int l0 = blockIdx.y * 32;

  for (int idx = tid; idx < 32 * 40; idx += 256) {
    int r = idx / 40, c4 = (idx % 40) << 2;
    *(float4*)&sdt[r][c4] = *(const float4*)&xdbl[(size_t)(l0 + r) * NE + c4];
  }
  for (int idx = tid; idx < 64 * 40; idx += 256) {
    int r = idx / 40, c4 = (idx % 40) << 2;
    *(float4*)&sw[r][c4] = *(const float4*)&dtw[(size_t)(d0 + r) * DR + c4];
  }
  __syncthreads();

  const int td = tid & 15;   // d varies fastest across lanes
  const int tl = tid >> 4;
  float acc[2][4];
#pragma unroll
  for (int i = 0; i < 2; ++i)
#pragma unroll
    for (int j = 0; j < 4; ++j) acc[i][j] = 0.f;

#pragma unroll 4
  for (int k4 = 0; k4 < DR; k4 += 4) {
    float a[2][4], b[4][4];
#pragma unroll
    for (int i = 0; i < 2; ++i)
      *(float4*)&a[i][0] = *(const float4*)&sdt[tl + 16 * i][k4];
#pragma unroll
    for (int j = 0; j < 4; ++j)
      *(float4*)&b[j][0] = *(const float4*)&sw[td + 16 * j][k4];
#pragma unroll
    for (int i = 0; i < 2; ++i)
#pragma unroll
      for (int j = 0; j < 4; ++j)
#pragma unroll
        for (int q = 0; q < 4; ++q)
          acc[i][j] += a[i][q] * b[j][q];
  }
#pragma unroll
  for (int i = 0; i < 2; ++i)
#pragma unroll
    for (int j = 0; j < 4; ++j) {
      int l = l0 + tl + 16 * i;
      int d = d0 + td + 16 * j;
      float z = acc[i][j] + dtb[d];
      float sp = fmaxf(z, 0.f) + log1pf(__expf(-fabsf(z)));
      delta[(size_t)l * DI + d] = sp;
    }
}

// ---------------- scan pass 1: per-chunk (prod a, h-from-zero)
__global__ __launch_bounds__(256) void k_scan1(const float* __restrict__ x,
                                               const float* __restrict__ delta,
                                               const float* __restrict__ xdbl,
                                               const float* __restrict__ A_log,
                                               float* __restrict__ hend,
                                               float* __restrict__ aprod) {
  const int d = blockIdx.x * 256 + threadIdx.x;
  const int c = blockIdx.y;
  __shared__ float sB[CL][DS];
  __shared__ float sC[CL][DS];
  for (int i = threadIdx.x; i < CL * DS; i += 256) {
    int t = i >> 4, n = i & 15;
    sB[t][n] = xdbl[(size_t)(c * CL + t) * NE + DR + n];
    sC[t][n] = xdbl[(size_t)(c * CL + t) * NE + DR + DS + n];
  }
  __syncthreads();
  float a[DS], h[DS], ap[DS];
#pragma unroll
  for (int n = 0; n < DS; ++n) {
    a[n] = -__expf(A_log[(size_t)d * DS + n]);
    h[n] = 0.f;
    ap[n] = 1.f;
  }
#pragma unroll 2
  for (int tt = 0; tt < CL; ++tt) {
    int t = c * CL + tt;
    float dl = delta[(size_t)t * DI + d];
    float xv = x[(size_t)t * DI + d];
    float du = dl * xv;
#pragma unroll
    for (int n = 0; n < DS; ++n) {
      float dA = __expf(dl * a[n]);
      h[n] = dA * h[n] + du * sB[tt][n];
      ap[n] *= dA;
    }
  }
#pragma unroll
  for (int n = 0; n < DS; ++n) {
    hend[(size_t)(c * DS + n) * DI + d] = h[n];
    aprod[(size_t)(c * DS + n) * DI + d] = ap[n];
  }
}

// ---------------- scan pass 2: sequential carry across chunks (in-place -> hstart)
__global__ __launch_bounds__(256) void k_scan2(float* __restrict__ hend,
                                               const float* __restrict__ aprod) {
  int i = blockIdx.x * 256 + threadIdx.x;   // i = n*DI + d, 81920 total, grid=320
  float carry = 0.f;
#pragma unroll
  for (int c = 0; c < NC; ++c) {
    size_t idx = (size_t)c * DS * DI + i;
    float apv = aprod[idx];
    float hv = hend[idx];
    hend[idx] = carry;                      // becomes hstart
    carry = apv * carry + hv;
  }
}

// ---------------- scan pass 3: exact replay from carry-in, emit y (f32 out)
__global__ __launch_bounds__(256) void k_scan3(const float* __restrict__ x,
                                               const float* __restrict__ delta,
                                               const float* __restrict__ xdbl,
                                               const float* __restrict__ A_log,
                                               const float* __restrict__ Dvec,
                                               const float* __restrict__ hstart,
                                               float* __restrict__ out) {
  const int d = blockIdx.x * 256 + threadIdx.x;
  const int c = blockIdx.y;
  __shared__ float sB[CL][DS];
  __shared__ float sC[CL][DS];
  for (int i = threadIdx.x; i < CL * DS; i += 256) {
    int t = i >> 4, n = i & 15;
    sB[t][n] = xdbl[(size_t)(c * CL + t) * NE + DR + n];
    sC[t][n] = xdbl[(size_t)(c * CL + t) * NE + DR + DS + n];
  }
  __syncthreads();
  float a[DS], h[DS];
#pragma unroll
  for (int n = 0; n < DS; ++n) {
    a[n] = -__expf(A_log[(size_t)d * DS + n]);
    h[n] = hstart[(size_t)(c * DS + n) * DI + d];
  }
  const float Dv = Dvec[d];
#pragma unroll 2
  for (int tt = 0; tt < CL; ++tt) {
    int t = c * CL + tt;
    float dl = delta[(size_t)t * DI + d];
    float xv = x[(size_t)t * DI + d];
    float du = dl * xv;
    float y = 0.f;
#pragma unroll
    for (int n = 0; n < DS; ++n) {
      float dA = __expf(dl * a[n]);
      h[n] = dA * h[n] + du * sB[tt][n];
      y += h[n] * sC[tt][n];
    }
    out[(size_t)t * DI + d] = fmaf(xv, Dv, y);   // FLOAT32 output (ref dtype)
  }
}

extern "C" void kernel_launch(void* const* d_in, const int* in_sizes, int n_in,
                              void* d_out, int out_size, void* d_ws, size_t ws_size,
                              hipStream_t stream) {
  const float* x     = (const float*)d_in[0];
  const float* A_log = (const float*)d_in[1];
  const float* Dvec  = (const float*)d_in[2];
  const float* xw    = (const float*)d_in[3];
  const float* dtw   = (const float*)d_in[4];
  const float* dtb   = (const float*)d_in[5];
  float* out = (float*)d_out;   // reference output dtype is float32

  char* ws = (char*)d_ws;
  float* part  = (float*)(ws + OFF_P);
  float* xdbl  = (float*)(ws + OFF_XDBL);
  float* delta = (float*)(ws + OFF_DELTA);
  float* hend  = (float*)(ws + OFF_HEND);
  float* aprod = (float*)(ws + OFF_APROD);

  k_xdbl<<<dim3(3, 16, SPLITK), 256, 0, stream>>>(x, xw, part);
  k_xdbl_reduce<<<768, 256, 0, stream>>>(part, xdbl);
  k_delta<<<dim3(80, 32), 256, 0, stream>>>(xdbl, dtw, dtb, delta);
  k_scan1<<<dim3(20, NC), 256, 0, stream>>>(x, delta, xdbl, A_log, hend, aprod);
  k_scan2<<<320, 256, 0, stream>>>(hend, aprod);
  k_scan3<<<dim3(20, NC), 256, 0, stream>>>(x, delta, xdbl, A_log, Dvec, hend, out);
}

// Round 6
// 157.742 us; speedup vs baseline: 1.2135x; 1.2135x over previous
//
#include <hip/hip_runtime.h>
#include <hip/hip_bf16.h>

#define L_SEQ 1024
#define DI    5120
#define DS    16
#define DR    160
#define NE    192      // DR + 2*DS
#define NC    16       // scan chunks
#define CL    64       // chunk length = L_SEQ/NC
#define SPLITK 8
#define KSPLIT (DI / SPLITK)   // 640

// workspace layout (bytes) — unchanged from round 5
#define OFF_P     0
#define SZ_P      (SPLITK * L_SEQ * NE * 4)   // 6,291,456
#define OFF_XDBL  (OFF_P + SZ_P)
#define SZ_XDBL   (L_SEQ * NE * 4)            // 786,432
#define OFF_DELTA (OFF_XDBL + SZ_XDBL)
#define SZ_DELTA  (L_SEQ * DI * 4)            // 20,971,520
#define OFF_HEND  (OFF_DELTA + SZ_DELTA)
#define SZ_H      (NC * DS * DI * 4)          // 5,242,880
#define OFF_APROD (OFF_HEND + SZ_H)
// total ~38.5 MB

typedef short s16x8 __attribute__((ext_vector_type(8)));   // 8 bf16 in 4 VGPRs
typedef float f32x4 __attribute__((ext_vector_type(4)));

__device__ __forceinline__ unsigned short bf_rn(float f) {
  unsigned u = __float_as_uint(f);
  u += 0x7FFFu + ((u >> 16) & 1u);      // round-to-nearest-even
  return (unsigned short)(u >> 16);
}

// load 8 consecutive f32 at p -> hi/lo bf16 fragments (hi+lo ~= f32 exactly)
__device__ __forceinline__ void load_hilo(const float* __restrict__ p,
                                          s16x8& hi, s16x8& lo) {
  float4 v0 = *(const float4*)p;
  float4 v1 = *(const float4*)(p + 4);
  float f[8] = {v0.x, v0.y, v0.z, v0.w, v1.x, v1.y, v1.z, v1.w};
#pragma unroll
  for (int j = 0; j < 8; ++j) {
    unsigned short h = bf_rn(f[j]);
    float hf = __uint_as_float(((unsigned)h) << 16);
    unsigned short l = bf_rn(f[j] - hf);
    hi[j] = (short)h;
    lo[j] = (short)l;
  }
}

// ---------------- GEMM1 (MFMA): part[z][l][e] = sum_{k in chunk z} x[l,k]*xw[e,k]
// wave tile 32(l)x32(e), 2 waves/block side-by-side in e; grid (192/64, 1024/32, SPLITK)
__global__ __launch_bounds__(128) void k_xdbl_mfma(const float* __restrict__ x,
                                                   const float* __restrict__ xw,
                                                   float* __restrict__ part) {
  const int lane = threadIdx.x & 63;
  const int w    = threadIdx.x >> 6;                 // 0..1
  const int e0   = blockIdx.x * 64 + w * 32;
  const int l0   = blockIdx.y * 32;
  const int kb   = blockIdx.z * KSPLIT;
  const int rc   = lane & 15;                        // row (A) / col (B) index
  const int kg   = (lane >> 4) * 8;                  // k-group offset

  f32x4 acc[2][2] = {};
  for (int k0 = 0; k0 < KSPLIT; k0 += 32) {
    s16x8 ahi[2], alo[2], bhi[2], blo[2];
#pragma unroll
    for (int mf = 0; mf < 2; ++mf)
      load_hilo(&x[(size_t)(l0 + mf * 16 + rc) * DI + kb + k0 + kg], ahi[mf], alo[mf]);
#pragma unroll
    for (int nf = 0; nf < 2; ++nf)
      load_hilo(&xw[(size_t)(e0 + nf * 16 + rc) * DI + kb + k0 + kg], bhi[nf], blo[nf]);
#pragma unroll
    for (int mf = 0; mf < 2; ++mf)
#pragma unroll
      for (int nf = 0; nf < 2; ++nf) {
        acc[mf][nf] = __builtin_amdgcn_mfma_f32_16x16x32_bf16(ahi[mf], bhi[nf], acc[mf][nf], 0, 0, 0);
        acc[mf][nf] = __builtin_amdgcn_mfma_f32_16x16x32_bf16(ahi[mf], blo[nf], acc[mf][nf], 0, 0, 0);
        acc[mf][nf] = __builtin_amdgcn_mfma_f32_16x16x32_bf16(alo[mf], bhi[nf], acc[mf][nf], 0, 0, 0);
      }
  }
#pragma unroll
  for (int mf = 0; mf < 2; ++mf)
#pragma unroll
    for (int nf = 0; nf < 2; ++nf)
#pragma unroll
      for (int r = 0; r < 4; ++r) {
        int l = l0 + mf * 16 + (lane >> 4) * 4 + r;   // C/D: row=(lane>>4)*4+reg
        int e = e0 + nf * 16 + rc;                    //      col=lane&15
        part[((size_t)blockIdx.z * L_SEQ + l) * NE + e] = acc[mf][nf][r];
      }
}

__global__ __launch_bounds__(256) void k_xdbl_reduce(const float* __restrict__ part,
                                                     float* __restrict__ xdbl) {
  int i = blockIdx.x * 256 + threadIdx.x;   // 196608 total, grid=768
  float s = 0.f;
#pragma unroll
  for (int z = 0; z < SPLITK; ++z) s += part[(size_t)z * L_SEQ * NE + i];
  xdbl[i] = s;
}

// ---------------- GEMM2 (MFMA): delta[l,d] = softplus(sum_r dt[l,r]*dtw[d,r] + b[d])
// wave tile 32(l)x32(d), 4 waves/block side-by-side in d; grid (5120/128, 1024/32)
__global__ __launch_bounds__(256) void k_delta_mfma(const float* __restrict__ xdbl,
                                                    const float* __restrict__ dtw,
                                                    const float* __restrict__ dtb,
                                                    float* __restrict__ delta) {
  const int lane = threadIdx.x & 63;
  const int w    = threadIdx.x >> 6;                 // 0..3
  const int d0   = blockIdx.x * 128 + w * 32;
  const int l0   = blockIdx.y * 32;
  const int rc   = lane & 15;
  const int kg   = (lane >> 4) * 8;

  f32x4 acc[2][2] = {};
#pragma unroll
  for (int k0 = 0; k0 < DR; k0 += 32) {
    s16x8 ahi[2], alo[2], bhi[2], blo[2];
#pragma unroll
    for (int mf = 0; mf < 2; ++mf)
      load_hilo(&xdbl[(size_t)(l0 + mf * 16 + rc) * NE + k0 + kg], ahi[mf], alo[mf]);
#pragma unroll
    for (int nf = 0; nf < 2; ++nf)
      load_hilo(&dtw[(size_t)(d0 + nf * 16 + rc) * DR + k0 + kg], bhi[nf], blo[nf]);
#pragma unroll
    for (int mf = 0; mf < 2; ++mf)
#pragma unroll
      for (int nf = 0; nf < 2; ++nf) {
        acc[mf][nf] = __builtin_amdgcn_mfma_f32_16x16x32_bf16(ahi[mf], bhi[nf], acc[mf][nf], 0, 0, 0);
        acc[mf][nf] = __builtin_amdgcn_mfma_f32_16x16x32_bf16(ahi[mf], blo[nf], acc[mf][nf], 0, 0, 0);
        acc[mf][nf] = __builtin_amdgcn_mfma_f32_16x16x32_bf16(alo[mf], bhi[nf], acc[mf][nf], 0, 0, 0);
      }
  }
#pragma unroll
  for (int nf = 0; nf < 2; ++nf) {
    int d = d0 + nf * 16 + rc;
    float bias = dtb[d];
#pragma unroll
    for (int mf = 0; mf < 2; ++mf)
#pragma unroll
      for (int r = 0; r < 4; ++r) {
        int l = l0 + mf * 16 + (lane >> 4) * 4 + r;
        float z = acc[mf][nf][r] + bias;
        float sp = fmaxf(z, 0.f) + log1pf(__expf(-fabsf(z)));
        delta[(size_t)l * DI + d] = sp;
      }
  }
}

// ---------------- scan pass 1: per-chunk (prod a, h-from-zero)
__global__ __launch_bounds__(256) void k_scan1(const float* __restrict__ x,
                                               const float* __restrict__ delta,
                                               const float* __restrict__ xdbl,
                                               const float* __restrict__ A_log,
                                               float* __restrict__ hend,
                                               float* __restrict__ aprod) {
  const int d = blockIdx.x * 256 + threadIdx.x;
  const int c = blockIdx.y;
  __shared__ float sB[CL][DS];
  __shared__ float sC[CL][DS];
  for (int i = threadIdx.x; i < CL * DS; i += 256) {
    int t = i >> 4, n = i & 15;
    sB[t][n] = xdbl[(size_t)(c * CL + t) * NE + DR + n];
    sC[t][n] = xdbl[(size_t)(c * CL + t) * NE + DR + DS + n];
  }
  __syncthreads();
  float a[DS], h[DS], ap[DS];
#pragma unroll
  for (int n = 0; n < DS; ++n) {
    a[n] = -__expf(A_log[(size_t)d * DS + n]);
    h[n] = 0.f;
    ap[n] = 1.f;
  }
#pragma unroll 2
  for (int tt = 0; tt < CL; ++tt) {
    int t = c * CL + tt;
    float dl = delta[(size_t)t * DI + d];
    float xv = x[(size_t)t * DI + d];
    float du = dl * xv;
#pragma unroll
    for (int n = 0; n < DS; ++n) {
      float dA = __expf(dl * a[n]);
      h[n] = dA * h[n] + du * sB[tt][n];
      ap[n] *= dA;
    }
  }
#pragma unroll
  for (int n = 0; n < DS; ++n) {
    hend[(size_t)(c * DS + n) * DI + d] = h[n];
    aprod[(size_t)(c * DS + n) * DI + d] = ap[n];
  }
}

// ---------------- scan pass 2: sequential carry across chunks (in-place -> hstart)
__global__ __launch_bounds__(256) void k_scan2(float* __restrict__ hend,
                                               const float* __restrict__ aprod) {
  int i = blockIdx.x * 256 + threadIdx.x;   // i = n*DI + d, 81920 total, grid=320
  float carry = 0.f;
#pragma unroll
  for (int c = 0; c < NC; ++c) {
    size_t idx = (size_t)c * DS * DI + i;
    float apv = aprod[idx];
    float hv = hend[idx];
    hend[idx] = carry;                      // becomes hstart
    carry = apv * carry + hv;
  }
}

// ---------------- scan pass 3: exact replay from carry-in, emit y (f32 out)
__global__ __launch_bounds__(256) void k_scan3(const float* __restrict__ x,
                                               const float* __restrict__ delta,
                                               const float* __restrict__ xdbl,
                                               const float* __restrict__ A_log,
                                               const float* __restrict__ Dvec,
                                               const float* __restrict__ hstart,
                                               float* __restrict__ out) {
  const int d = blockIdx.x * 256 + threadIdx.x;
  const int c = blockIdx.y;
  __shared__ float sB[CL][DS];
  __shared__ float sC[CL][DS];
  for (int i = threadIdx.x; i < CL * DS; i += 256) {
    int t = i >> 4, n = i & 15;
    sB[t][n] = xdbl[(size_t)(c * CL + t) * NE + DR + n];
    sC[t][n] = xdbl[(size_t)(c * CL + t) * NE + DR + DS + n];
  }
  __syncthreads();
  float a[DS], h[DS];
#pragma unroll
  for (int n = 0; n < DS; ++n) {
    a[n] = -__expf(A_log[(size_t)d * DS + n]);
    h[n] = hstart[(size_t)(c * DS + n) * DI + d];
  }
  const float Dv = Dvec[d];
#pragma unroll 2
  for (int tt = 0; tt < CL; ++tt) {
    int t = c * CL + tt;
    float dl = delta[(size_t)t * DI + d];
    float xv = x[(size_t)t * DI + d];
    float du = dl * xv;
    float y = 0.f;
#pragma unroll
    for (int n = 0; n < DS; ++n) {
      float dA = __expf(dl * a[n]);
      h[n] = dA * h[n] + du * sB[tt][n];
      y += h[n] * sC[tt][n];
    }
    out[(size_t)t * DI + d] = fmaf(xv, Dv, y);   // FLOAT32 output (ref dtype)
  }
}

extern "C" void kernel_launch(void* const* d_in, const int* in_sizes, int n_in,
                              void* d_out, int out_size, void* d_ws, size_t ws_size,
                              hipStream_t stream) {
  const float* x     = (const float*)d_in[0];
  const float* A_log = (const float*)d_in[1];
  const float* Dvec  = (const float*)d_in[2];
  const float* xw    = (const float*)d_in[3];
  const float* dtw   = (const float*)d_in[4];
  const float* dtb   = (const float*)d_in[5];
  float* out = (float*)d_out;   // reference output dtype is float32

  char* ws = (char*)d_ws;
  float* part  = (float*)(ws + OFF_P);
  float* xdbl  = (float*)(ws + OFF_XDBL);
  float* delta = (float*)(ws + OFF_DELTA);
  float* hend  = (float*)(ws + OFF_HEND);
  float* aprod = (float*)(ws + OFF_APROD);

  k_xdbl_mfma<<<dim3(3, 32, SPLITK), 128, 0, stream>>>(x, xw, part);
  k_xdbl_reduce<<<768, 256, 0, stream>>>(part, xdbl);
  k_delta_mfma<<<dim3(40, 32), 256, 0, stream>>>(xdbl, dtw, dtb, delta);
  k_scan1<<<dim3(20, NC), 256, 0, stream>>>(x, delta, xdbl, A_log, hend, aprod);
  k_scan2<<<320, 256, 0, stream>>>(hend, aprod);
  k_scan3<<<dim3(20, NC), 256, 0, stream>>>(x, delta, xdbl, A_log, Dvec, hend, out);
}

// Round 7
// 142.025 us; speedup vs baseline: 1.3478x; 1.1107x over previous
//
#include <hip/hip_runtime.h>
#include <hip/hip_bf16.h>

#define L_SEQ 1024
#define DI    5120
#define DS    16
#define DR    160
#define NE    192      // DR + 2*DS
#define NC    16       // scan chunks
#define CL    64       // chunk length = L_SEQ/NC
#define SPLITK 8
#define KSPLIT (DI / SPLITK)   // 640

// workspace layout (bytes)
#define OFF_P     0
#define SZ_P      (SPLITK * L_SEQ * NE * 4)   // 6,291,456
#define OFF_XDBL  (OFF_P + SZ_P)
#define SZ_XDBL   (L_SEQ * NE * 4)            // 786,432
#define OFF_DELTA (OFF_XDBL + SZ_XDBL)
#define SZ_DELTA  (L_SEQ * DI * 4)            // 20,971,520
#define OFF_HEND  (OFF_DELTA + SZ_DELTA)
#define SZ_H      (NC * DS * DI * 4)          // 5,242,880
#define OFF_APROD (OFF_HEND + SZ_H)
// bf16 hi/lo planes live in the hend region (dead until k_scan1):
#define OFF_WH    OFF_HEND                     // dtw hi: 1,638,400 B
#define OFF_WL    (OFF_WH + 1638400)           // dtw lo: 1,638,400 B
#define OFF_XH    (OFF_WL + 1638400)           // xdbl hi: 393,216 B
#define OFF_XL    (OFF_XH + 393216)            // xdbl lo: 393,216 B  (total 4.06MB < 5.24MB)

typedef short s16x8 __attribute__((ext_vector_type(8)));   // 8 bf16 in 4 VGPRs
typedef float f32x4 __attribute__((ext_vector_type(4)));

__device__ __forceinline__ unsigned short bf_rn(float f) {
  unsigned u = __float_as_uint(f);
  u += 0x7FFFu + ((u >> 16) & 1u);      // round-to-nearest-even
  return (unsigned short)(u >> 16);
}
__device__ __forceinline__ void split_hilo(float f, unsigned short& h, unsigned short& l) {
  h = bf_rn(f);
  float hf = __uint_as_float(((unsigned)h) << 16);
  l = bf_rn(f - hf);
}

// load 8 consecutive f32 at p -> hi/lo bf16 fragments (hi+lo ~= f32)
__device__ __forceinline__ void load_hilo(const float* __restrict__ p,
                                          s16x8& hi, s16x8& lo) {
  float4 v0 = *(const float4*)p;
  float4 v1 = *(const float4*)(p + 4);
  float f[8] = {v0.x, v0.y, v0.z, v0.w, v1.x, v1.y, v1.z, v1.w};
#pragma unroll
  for (int j = 0; j < 8; ++j) {
    unsigned short h, l;
    split_hilo(f[j], h, l);
    hi[j] = (short)h;
    lo[j] = (short)l;
  }
}

// ---------------- cvt: dtw f32 -> bf16 hi/lo planes (819200 elems, 4/thread)
__global__ __launch_bounds__(256) void k_cvt(const float* __restrict__ src,
                                             unsigned short* __restrict__ hi,
                                             unsigned short* __restrict__ lo) {
  int i4 = (blockIdx.x * 256 + threadIdx.x) * 4;   // grid 800 -> exact
  float4 v = *(const float4*)&src[i4];
  float f[4] = {v.x, v.y, v.z, v.w};
  ushort4 h, l;
  unsigned short hh, ll;
  split_hilo(f[0], hh, ll); h.x = hh; l.x = ll;
  split_hilo(f[1], hh, ll); h.y = hh; l.y = ll;
  split_hilo(f[2], hh, ll); h.z = hh; l.z = ll;
  split_hilo(f[3], hh, ll); h.w = hh; l.w = ll;
  *(ushort4*)&hi[i4] = h;
  *(ushort4*)&lo[i4] = l;
}

// ---------------- GEMM1 (MFMA): part[z][l][e] = sum_{k in chunk z} x[l,k]*xw[e,k]
__global__ __launch_bounds__(128) void k_xdbl_mfma(const float* __restrict__ x,
                                                   const float* __restrict__ xw,
                                                   float* __restrict__ part) {
  const int lane = threadIdx.x & 63;
  const int w    = threadIdx.x >> 6;                 // 0..1
  const int e0   = blockIdx.x * 64 + w * 32;
  const int l0   = blockIdx.y * 32;
  const int kb   = blockIdx.z * KSPLIT;
  const int rc   = lane & 15;
  const int kg   = (lane >> 4) * 8;

  f32x4 acc[2][2] = {};
  for (int k0 = 0; k0 < KSPLIT; k0 += 32) {
    s16x8 ahi[2], alo[2], bhi[2], blo[2];
#pragma unroll
    for (int mf = 0; mf < 2; ++mf)
      load_hilo(&x[(size_t)(l0 + mf * 16 + rc) * DI + kb + k0 + kg], ahi[mf], alo[mf]);
#pragma unroll
    for (int nf = 0; nf < 2; ++nf)
      load_hilo(&xw[(size_t)(e0 + nf * 16 + rc) * DI + kb + k0 + kg], bhi[nf], blo[nf]);
#pragma unroll
    for (int mf = 0; mf < 2; ++mf)
#pragma unroll
      for (int nf = 0; nf < 2; ++nf) {
        acc[mf][nf] = __builtin_amdgcn_mfma_f32_16x16x32_bf16(ahi[mf], bhi[nf], acc[mf][nf], 0, 0, 0);
        acc[mf][nf] = __builtin_amdgcn_mfma_f32_16x16x32_bf16(ahi[mf], blo[nf], acc[mf][nf], 0, 0, 0);
        acc[mf][nf] = __builtin_amdgcn_mfma_f32_16x16x32_bf16(alo[mf], bhi[nf], acc[mf][nf], 0, 0, 0);
      }
  }
#pragma unroll
  for (int mf = 0; mf < 2; ++mf)
#pragma unroll
    for (int nf = 0; nf < 2; ++nf)
#pragma unroll
      for (int r = 0; r < 4; ++r) {
        int l = l0 + mf * 16 + (lane >> 4) * 4 + r;   // C/D: row=(lane>>4)*4+reg
        int e = e0 + nf * 16 + rc;                    //      col=lane&15
        part[((size_t)blockIdx.z * L_SEQ + l) * NE + e] = acc[mf][nf][r];
      }
}

// ---------------- reduce split-K partials; also emit xdbl bf16 hi/lo planes
__global__ __launch_bounds__(256) void k_xdbl_reduce(const float* __restrict__ part,
                                                     float* __restrict__ xdbl,
                                                     unsigned short* __restrict__ xh,
                                                     unsigned short* __restrict__ xl) {
  int i4 = (blockIdx.x * 256 + threadIdx.x) * 4;   // 49152 threads, grid=192
  float4 s = {0.f, 0.f, 0.f, 0.f};
#pragma unroll
  for (int z = 0; z < SPLITK; ++z) {
    float4 p = *(const float4*)&part[(size_t)z * L_SEQ * NE + i4];
    s.x += p.x; s.y += p.y; s.z += p.z; s.w += p.w;
  }
  *(float4*)&xdbl[i4] = s;
  float f[4] = {s.x, s.y, s.z, s.w};
  ushort4 h, l;
  unsigned short hh, ll;
  split_hilo(f[0], hh, ll); h.x = hh; l.x = ll;
  split_hilo(f[1], hh, ll); h.y = hh; l.y = ll;
  split_hilo(f[2], hh, ll); h.z = hh; l.z = ll;
  split_hilo(f[3], hh, ll); h.w = hh; l.w = ll;
  *(ushort4*)&xh[i4] = h;
  *(ushort4*)&xl[i4] = l;
}

// ---------------- GEMM2 (MFMA, preconverted bf16): delta = softplus(dt·dtw^T + b)
// block = 512 thr / 8 waves; tile 64(l) x 128(d); wave = 32l x 32d
#define AST 168   // LDS A row stride in shorts (336B: 2-way max bank aliasing, 16B aligned)
__global__ __launch_bounds__(512) void k_delta_mfma2(const unsigned short* __restrict__ xh,
                                                     const unsigned short* __restrict__ xl,
                                                     const unsigned short* __restrict__ wh,
                                                     const unsigned short* __restrict__ wlo,
                                                     const float* __restrict__ dtb,
                                                     float* __restrict__ delta) {
  __shared__ unsigned short sAh[64 * AST];
  __shared__ unsigned short sAl[64 * AST];
  const int tid  = threadIdx.x;
  const int lane = tid & 63;
  const int w    = tid >> 6;            // 0..7
  const int wl_  = w >> 2;              // l-subtile 0..1
  const int wd   = w & 3;               // d-subtile 0..3
  const int l0   = blockIdx.y * 64;
  const int d0   = blockIdx.x * 128 + wd * 32;
  const int rc   = lane & 15;
  const int kg   = (lane >> 4) * 8;

  // stage A rows l0..l0+63, cols 0..159 (16B chunks; both planes)
  for (int idx = tid; idx < 64 * 20; idx += 512) {
    int r = idx / 20, c8 = (idx % 20) * 8;
    *(s16x8*)&sAh[r * AST + c8] = *(const s16x8*)&xh[(size_t)(l0 + r) * NE + c8];
    *(s16x8*)&sAl[r * AST + c8] = *(const s16x8*)&xl[(size_t)(l0 + r) * NE + c8];
  }
  __syncthreads();

  f32x4 acc[2][2] = {};
#pragma unroll
  for (int k0 = 0; k0 < DR; k0 += 32) {
    s16x8 ah[2], al[2], bh[2], bl[2];
#pragma unroll
    for (int mf = 0; mf < 2; ++mf) {
      int row = wl_ * 32 + mf * 16 + rc;
      ah[mf] = *(const s16x8*)&sAh[row * AST + k0 + kg];
      al[mf] = *(const s16x8*)&sAl[row * AST + k0 + kg];
    }
#pragma unroll
    for (int nf = 0; nf < 2; ++nf) {
      size_t d = d0 + nf * 16 + rc;
      bh[nf] = *(const s16x8*)&wh[d * DR + k0 + kg];
      bl[nf] = *(const s16x8*)&wlo[d * DR + k0 + kg];
    }
#pragma unroll
    for (int mf = 0; mf < 2; ++mf)
#pragma unroll
      for (int nf = 0; nf < 2; ++nf) {
        acc[mf][nf] = __builtin_amdgcn_mfma_f32_16x16x32_bf16(ah[mf], bh[nf], acc[mf][nf], 0, 0, 0);
        acc[mf][nf] = __builtin_amdgcn_mfma_f32_16x16x32_bf16(ah[mf], bl[nf], acc[mf][nf], 0, 0, 0);
        acc[mf][nf] = __builtin_amdgcn_mfma_f32_16x16x32_bf16(al[mf], bh[nf], acc[mf][nf], 0, 0, 0);
      }
  }
#pragma unroll
  for (int nf = 0; nf < 2; ++nf) {
    int d = d0 + nf * 16 + rc;
    float bias = dtb[d];
#pragma unroll
    for (int mf = 0; mf < 2; ++mf)
#pragma unroll
      for (int r = 0; r < 4; ++r) {
        int l = l0 + wl_ * 32 + mf * 16 + (lane >> 4) * 4 + r;
        float z = acc[mf][nf][r] + bias;
        float sp = fmaxf(z, 0.f) + __logf(1.f + __expf(-fabsf(z)));
        delta[(size_t)l * DI + d] = sp;
      }
  }
}

// ---------------- scan pass 1: per-chunk (prod a, h-from-zero)
__global__ __launch_bounds__(256) void k_scan1(const float* __restrict__ x,
                                               const float* __restrict__ delta,
                                               const float* __restrict__ xdbl,
                                               const float* __restrict__ A_log,
                                               float* __restrict__ hend,
                                               float* __restrict__ aprod) {
  const int d = blockIdx.x * 256 + threadIdx.x;
  const int c = blockIdx.y;
  __shared__ float sB[CL][DS];
  __shared__ float sC[CL][DS];
  for (int i = threadIdx.x; i < CL * DS; i += 256) {
    int t = i >> 4, n = i & 15;
    sB[t][n] = xdbl[(size_t)(c * CL + t) * NE + DR + n];
    sC[t][n] = xdbl[(size_t)(c * CL + t) * NE + DR + DS + n];
  }
  __syncthreads();
  float a[DS], h[DS], ap[DS];
#pragma unroll
  for (int n = 0; n < DS; ++n) {
    a[n] = -__expf(A_log[(size_t)d * DS + n]);
    h[n] = 0.f;
    ap[n] = 1.f;
  }
#pragma unroll 2
  for (int tt = 0; tt < CL; ++tt) {
    int t = c * CL + tt;
    float dl = delta[(size_t)t * DI + d];
    float xv = x[(size_t)t * DI + d];
    float du = dl * xv;
#pragma unroll
    for (int n = 0; n < DS; ++n) {
      float dA = __expf(dl * a[n]);
      h[n] = dA * h[n] + du * sB[tt][n];
      ap[n] *= dA;
    }
  }
#pragma unroll
  for (int n = 0; n < DS; ++n) {
    hend[(size_t)(c * DS + n) * DI + d] = h[n];
    aprod[(size_t)(c * DS + n) * DI + d] = ap[n];
  }
}

// ---------------- scan pass 2: sequential carry across chunks (in-place -> hstart)
__global__ __launch_bounds__(256) void k_scan2(float* __restrict__ hend,
                                               const float* __restrict__ aprod) {
  int i = blockIdx.x * 256 + threadIdx.x;   // i = n*DI + d, 81920 total, grid=320
  float carry = 0.f;
#pragma unroll
  for (int c = 0; c < NC; ++c) {
    size_t idx = (size_t)c * DS * DI + i;
    float apv = aprod[idx];
    float hv = hend[idx];
    hend[idx] = carry;                      // becomes hstart
    carry = apv * carry + hv;
  }
}

// ---------------- scan pass 3: exact replay from carry-in, emit y (f32 out)
__global__ __launch_bounds__(256) void k_scan3(const float* __restrict__ x,
                                               const float* __restrict__ delta,
                                               const float* __restrict__ xdbl,
                                               const float* __restrict__ A_log,
                                               const float* __restrict__ Dvec,
                                               const float* __restrict__ hstart,
                                               float* __restrict__ out) {
  const int d = blockIdx.x * 256 + threadIdx.x;
  const int c = blockIdx.y;
  __shared__ float sB[CL][DS];
  __shared__ float sC[CL][DS];
  for (int i = threadIdx.x; i < CL * DS; i += 256) {
    int t = i >> 4, n = i & 15;
    sB[t][n] = xdbl[(size_t)(c * CL + t) * NE + DR + n];
    sC[t][n] = xdbl[(size_t)(c * CL + t) * NE + DR + DS + n];
  }
  __syncthreads();
  float a[DS], h[DS];
#pragma unroll
  for (int n = 0; n < DS; ++n) {
    a[n] = -__expf(A_log[(size_t)d * DS + n]);
    h[n] = hstart[(size_t)(c * DS + n) * DI + d];
  }
  const float Dv = Dvec[d];
#pragma unroll 2
  for (int tt = 0; tt < CL; ++tt) {
    int t = c * CL + tt;
    float dl = delta[(size_t)t * DI + d];
    float xv = x[(size_t)t * DI + d];
    float du = dl * xv;
    float y = 0.f;
#pragma unroll
    for (int n = 0; n < DS; ++n) {
      float dA = __expf(dl * a[n]);
      h[n] = dA * h[n] + du * sB[tt][n];
      y += h[n] * sC[tt][n];
    }
    out[(size_t)t * DI + d] = fmaf(xv, Dv, y);   // FLOAT32 output (ref dtype)
  }
}

extern "C" void kernel_launch(void* const* d_in, const int* in_sizes, int n_in,
                              void* d_out, int out_size, void* d_ws, size_t ws_size,
                              hipStream_t stream) {
  const float* x     = (const float*)d_in[0];
  const float* A_log = (const float*)d_in[1];
  const float* Dvec  = (const float*)d_in[2];
  const float* xw    = (const float*)d_in[3];
  const float* dtw   = (const float*)d_in[4];
  const float* dtb   = (const float*)d_in[5];
  float* out = (float*)d_out;   // reference output dtype is float32

  char* ws = (char*)d_ws;
  float* part  = (float*)(ws + OFF_P);
  float* xdbl  = (float*)(ws + OFF_XDBL);
  float* delta = (float*)(ws + OFF_DELTA);
  float* hend  = (float*)(ws + OFF_HEND);
  float* aprod = (float*)(ws + OFF_APROD);
  unsigned short* wh = (unsigned short*)(ws + OFF_WH);
  unsigned short* wl = (unsigned short*)(ws + OFF_WL);
  unsigned short* xh = (unsigned short*)(ws + OFF_XH);
  unsigned short* xl = (unsigned short*)(ws + OFF_XL);

  k_cvt<<<800, 256, 0, stream>>>(dtw, wh, wl);
  k_xdbl_mfma<<<dim3(3, 32, SPLITK), 128, 0, stream>>>(x, xw, part);
  k_xdbl_reduce<<<192, 256, 0, stream>>>(part, xdbl, xh, xl);
  k_delta_mfma2<<<dim3(40, 16), 512, 0, stream>>>(xh, xl, wh, wl, dtb, delta);
  k_scan1<<<dim3(20, NC), 256, 0, stream>>>(x, delta, xdbl, A_log, hend, aprod);
  k_scan2<<<320, 256, 0, stream>>>(hend, aprod);
  k_scan3<<<dim3(20, NC), 256, 0, stream>>>(x, delta, xdbl, A_log, Dvec, hend, out);
}

// Round 8
// 113.810 us; speedup vs baseline: 1.6819x; 1.2479x over previous
//
#include <hip/hip_runtime.h>
#include <hip/hip_bf16.h>

#define L_SEQ 1024
#define DI    5120
#define DS    16
#define DR    160
#define NE    192      // DR + 2*DS
#define NC    16       // scan chunks
#define CL    64       // chunk length = L_SEQ/NC
#define SPLITK 8
#define KSPLIT (DI / SPLITK)   // 640

// workspace layout (bytes) — unchanged
#define OFF_P     0
#define SZ_P      (SPLITK * L_SEQ * NE * 4)   // 6,291,456
#define OFF_XDBL  (OFF_P + SZ_P)
#define SZ_XDBL   (L_SEQ * NE * 4)            // 786,432
#define OFF_DELTA (OFF_XDBL + SZ_XDBL)
#define SZ_DELTA  (L_SEQ * DI * 4)            // 20,971,520
#define OFF_HEND  (OFF_DELTA + SZ_DELTA)
#define SZ_H      (NC * DS * DI * 4)          // 5,242,880
#define OFF_APROD (OFF_HEND + SZ_H)
// bf16 hi/lo planes live in the hend region (dead until k_scan1):
#define OFF_WH    OFF_HEND                     // dtw hi: 1,638,400 B
#define OFF_WL    (OFF_WH + 1638400)           // dtw lo: 1,638,400 B
#define OFF_XH    (OFF_WL + 1638400)           // xdbl hi: 393,216 B
#define OFF_XL    (OFF_XH + 393216)            // xdbl lo: 393,216 B

typedef short s16x8 __attribute__((ext_vector_type(8)));   // 8 bf16 in 4 VGPRs
typedef float f32x4 __attribute__((ext_vector_type(4)));

__device__ __forceinline__ unsigned short bf_rn(float f) {
  unsigned u = __float_as_uint(f);
  u += 0x7FFFu + ((u >> 16) & 1u);      // round-to-nearest-even
  return (unsigned short)(u >> 16);
}
__device__ __forceinline__ void split_hilo(float f, unsigned short& h, unsigned short& l) {
  h = bf_rn(f);
  float hf = __uint_as_float(((unsigned)h) << 16);
  l = bf_rn(f - hf);
}

// load 8 consecutive f32 at p -> hi/lo bf16 fragments (hi+lo ~= f32)
__device__ __forceinline__ void load_hilo(const float* __restrict__ p,
                                          s16x8& hi, s16x8& lo) {
  float4 v0 = *(const float4*)p;
  float4 v1 = *(const float4*)(p + 4);
  float f[8] = {v0.x, v0.y, v0.z, v0.w, v1.x, v1.y, v1.z, v1.w};
#pragma unroll
  for (int j = 0; j < 8; ++j) {
    unsigned short h, l;
    split_hilo(f[j], h, l);
    hi[j] = (short)h;
    lo[j] = (short)l;
  }
}

// ---------------- cvt: dtw f32 -> bf16 hi/lo planes
__global__ __launch_bounds__(256) void k_cvt(const float* __restrict__ src,
                                             unsigned short* __restrict__ hi,
                                             unsigned short* __restrict__ lo) {
  int i4 = (blockIdx.x * 256 + threadIdx.x) * 4;
  float4 v = *(const float4*)&src[i4];
  float f[4] = {v.x, v.y, v.z, v.w};
  ushort4 h, l;
  unsigned short hh, ll;
  split_hilo(f[0], hh, ll); h.x = hh; l.x = ll;
  split_hilo(f[1], hh, ll); h.y = hh; l.y = ll;
  split_hilo(f[2], hh, ll); h.z = hh; l.z = ll;
  split_hilo(f[3], hh, ll); h.w = hh; l.w = ll;
  *(ushort4*)&hi[i4] = h;
  *(ushort4*)&lo[i4] = l;
}

// ---------------- GEMM1 (MFMA): part[z][l][e] = sum_{k in chunk z} x[l,k]*xw[e,k]
__global__ __launch_bounds__(128) void k_xdbl_mfma(const float* __restrict__ x,
                                                   const float* __restrict__ xw,
                                                   float* __restrict__ part) {
  const int lane = threadIdx.x & 63;
  const int w    = threadIdx.x >> 6;                 // 0..1
  const int e0   = blockIdx.x * 64 + w * 32;
  const int l0   = blockIdx.y * 32;
  const int kb   = blockIdx.z * KSPLIT;
  const int rc   = lane & 15;
  const int kg   = (lane >> 4) * 8;

  f32x4 acc[2][2] = {};
  for (int k0 = 0; k0 < KSPLIT; k0 += 32) {
    s16x8 ahi[2], alo[2], bhi[2], blo[2];
#pragma unroll
    for (int mf = 0; mf < 2; ++mf)
      load_hilo(&x[(size_t)(l0 + mf * 16 + rc) * DI + kb + k0 + kg], ahi[mf], alo[mf]);
#pragma unroll
    for (int nf = 0; nf < 2; ++nf)
      load_hilo(&xw[(size_t)(e0 + nf * 16 + rc) * DI + kb + k0 + kg], bhi[nf], blo[nf]);
#pragma unroll
    for (int mf = 0; mf < 2; ++mf)
#pragma unroll
      for (int nf = 0; nf < 2; ++nf) {
        acc[mf][nf] = __builtin_amdgcn_mfma_f32_16x16x32_bf16(ahi[mf], bhi[nf], acc[mf][nf], 0, 0, 0);
        acc[mf][nf] = __builtin_amdgcn_mfma_f32_16x16x32_bf16(ahi[mf], blo[nf], acc[mf][nf], 0, 0, 0);
        acc[mf][nf] = __builtin_amdgcn_mfma_f32_16x16x32_bf16(alo[mf], bhi[nf], acc[mf][nf], 0, 0, 0);
      }
  }
#pragma unroll
  for (int mf = 0; mf < 2; ++mf)
#pragma unroll
    for (int nf = 0; nf < 2; ++nf)
#pragma unroll
      for (int r = 0; r < 4; ++r) {
        int l = l0 + mf * 16 + (lane >> 4) * 4 + r;   // C/D: row=(lane>>4)*4+reg
        int e = e0 + nf * 16 + rc;                    //      col=lane&15
        part[((size_t)blockIdx.z * L_SEQ + l) * NE + e] = acc[mf][nf][r];
      }
}

// ---------------- reduce split-K partials; also emit xdbl bf16 hi/lo planes
__global__ __launch_bounds__(256) void k_xdbl_reduce(const float* __restrict__ part,
                                                     float* __restrict__ xdbl,
                                                     unsigned short* __restrict__ xh,
                                                     unsigned short* __restrict__ xl) {
  int i4 = (blockIdx.x * 256 + threadIdx.x) * 4;   // grid=192
  float4 s = {0.f, 0.f, 0.f, 0.f};
#pragma unroll
  for (int z = 0; z < SPLITK; ++z) {
    float4 p = *(const float4*)&part[(size_t)z * L_SEQ * NE + i4];
    s.x += p.x; s.y += p.y; s.z += p.z; s.w += p.w;
  }
  *(float4*)&xdbl[i4] = s;
  float f[4] = {s.x, s.y, s.z, s.w};
  ushort4 h, l;
  unsigned short hh, ll;
  split_hilo(f[0], hh, ll); h.x = hh; l.x = ll;
  split_hilo(f[1], hh, ll); h.y = hh; l.y = ll;
  split_hilo(f[2], hh, ll); h.z = hh; l.z = ll;
  split_hilo(f[3], hh, ll); h.w = hh; l.w = ll;
  *(ushort4*)&xh[i4] = h;
  *(ushort4*)&xl[i4] = l;
}

// ---------------- GEMM2 (MFMA, preconverted bf16): delta = softplus(dt·dtw^T + b)
#define AST 168
__global__ __launch_bounds__(512) void k_delta_mfma2(const unsigned short* __restrict__ xh,
                                                     const unsigned short* __restrict__ xl,
                                                     const unsigned short* __restrict__ wh,
                                                     const unsigned short* __restrict__ wlo,
                                                     const float* __restrict__ dtb,
                                                     float* __restrict__ delta) {
  __shared__ unsigned short sAh[64 * AST];
  __shared__ unsigned short sAl[64 * AST];
  const int tid  = threadIdx.x;
  const int lane = tid & 63;
  const int w    = tid >> 6;
  const int wl_  = w >> 2;
  const int wd   = w & 3;
  const int l0   = blockIdx.y * 64;
  const int d0   = blockIdx.x * 128 + wd * 32;
  const int rc   = lane & 15;
  const int kg   = (lane >> 4) * 8;

  for (int idx = tid; idx < 64 * 20; idx += 512) {
    int r = idx / 20, c8 = (idx % 20) * 8;
    *(s16x8*)&sAh[r * AST + c8] = *(const s16x8*)&xh[(size_t)(l0 + r) * NE + c8];
    *(s16x8*)&sAl[r * AST + c8] = *(const s16x8*)&xl[(size_t)(l0 + r) * NE + c8];
  }
  __syncthreads();

  f32x4 acc[2][2] = {};
#pragma unroll
  for (int k0 = 0; k0 < DR; k0 += 32) {
    s16x8 ah[2], al[2], bh[2], bl[2];
#pragma unroll
    for (int mf = 0; mf < 2; ++mf) {
      int row = wl_ * 32 + mf * 16 + rc;
      ah[mf] = *(const s16x8*)&sAh[row * AST + k0 + kg];
      al[mf] = *(const s16x8*)&sAl[row * AST + k0 + kg];
    }
#pragma unroll
    for (int nf = 0; nf < 2; ++nf) {
      size_t d = d0 + nf * 16 + rc;
      bh[nf] = *(const s16x8*)&wh[d * DR + k0 + kg];
      bl[nf] = *(const s16x8*)&wlo[d * DR + k0 + kg];
    }
#pragma unroll
    for (int mf = 0; mf < 2; ++mf)
#pragma unroll
      for (int nf = 0; nf < 2; ++nf) {
        acc[mf][nf] = __builtin_amdgcn_mfma_f32_16x16x32_bf16(ah[mf], bh[nf], acc[mf][nf], 0, 0, 0);
        acc[mf][nf] = __builtin_amdgcn_mfma_f32_16x16x32_bf16(ah[mf], bl[nf], acc[mf][nf], 0, 0, 0);
        acc[mf][nf] = __builtin_amdgcn_mfma_f32_16x16x32_bf16(al[mf], bh[nf], acc[mf][nf], 0, 0, 0);
      }
  }
#pragma unroll
  for (int nf = 0; nf < 2; ++nf) {
    int d = d0 + nf * 16 + rc;
    float bias = dtb[d];
#pragma unroll
    for (int mf = 0; mf < 2; ++mf)
#pragma unroll
      for (int r = 0; r < 4; ++r) {
        int l = l0 + wl_ * 32 + mf * 16 + (lane >> 4) * 4 + r;
        float z = acc[mf][nf][r] + bias;
        float sp = fmaxf(z, 0.f) + __logf(1.f + __expf(-fabsf(z)));
        delta[(size_t)l * DI + d] = sp;
      }
  }
}

// ---------------- scan pass 1 (4-way n-split): per-chunk (prod a via exp(a*sum_dl), h-from-zero)
// block 256 = 4 waves; wave: 16 d (lane&15) x 4 ng (lane>>4), 4 n-states/thread
__global__ __launch_bounds__(256) void k_scan1(const float* __restrict__ x,
                                               const float* __restrict__ delta,
                                               const float* __restrict__ xdbl,
                                               const float* __restrict__ A_log,
                                               float* __restrict__ hend,
                                               float* __restrict__ aprod) {
  const int lane = threadIdx.x & 63;
  const int w    = threadIdx.x >> 6;
  const int d    = blockIdx.x * 64 + w * 16 + (lane & 15);
  const int ng   = lane >> 4;                 // n-group: states ng*4..ng*4+3
  const int c    = blockIdx.y;
  __shared__ __align__(16) float sB[CL][DS];
  for (int i = threadIdx.x; i < CL * DS; i += 256) {
    int t = i >> 4, n = i & 15;
    sB[t][n] = xdbl[(size_t)(c * CL + t) * NE + DR + n];
  }
  __syncthreads();
  float4 av = *(const float4*)&A_log[(size_t)d * DS + ng * 4];
  float a[4] = {-__expf(av.x), -__expf(av.y), -__expf(av.z), -__expf(av.w)};
  float h[4] = {0.f, 0.f, 0.f, 0.f};
  float sdl = 0.f;

  const float* dp = &delta[(size_t)(c * CL) * DI + d];
  const float* xp = &x[(size_t)(c * CL) * DI + d];
  float dl = dp[0], xv = xp[0];
#pragma unroll 4
  for (int tt = 0; tt < CL; ++tt) {
    float dl_n = 0.f, xv_n = 0.f;
    if (tt + 1 < CL) { dl_n = dp[(size_t)(tt + 1) * DI]; xv_n = xp[(size_t)(tt + 1) * DI]; }
    float du = dl * xv;
    sdl += dl;
    float4 b4 = *(const float4*)&sB[tt][ng * 4];
    float bb[4] = {b4.x, b4.y, b4.z, b4.w};
#pragma unroll
    for (int j = 0; j < 4; ++j) {
      float dA = __expf(dl * a[j]);
      h[j] = dA * h[j] + du * bb[j];
    }
    dl = dl_n; xv = xv_n;
  }
#pragma unroll
  for (int j = 0; j < 4; ++j) {
    int n = ng * 4 + j;
    hend[(size_t)(c * DS + n) * DI + d] = h[j];
    aprod[(size_t)(c * DS + n) * DI + d] = __expf(a[j] * sdl);
  }
}

// ---------------- scan pass 2: sequential carry across chunks (in-place -> hstart)
__global__ __launch_bounds__(256) void k_scan2(float* __restrict__ hend,
                                               const float* __restrict__ aprod) {
  int i = blockIdx.x * 256 + threadIdx.x;   // 81920 total, grid=320
  float carry = 0.f;
#pragma unroll
  for (int c = 0; c < NC; ++c) {
    size_t idx = (size_t)c * DS * DI + i;
    float apv = aprod[idx];
    float hv = hend[idx];
    hend[idx] = carry;
    carry = apv * carry + hv;
  }
}

// ---------------- scan pass 3 (4-way n-split): replay from carry-in, emit y (f32)
__global__ __launch_bounds__(256) void k_scan3(const float* __restrict__ x,
                                               const float* __restrict__ delta,
                                               const float* __restrict__ xdbl,
                                               const float* __restrict__ A_log,
                                               const float* __restrict__ Dvec,
                                               const float* __restrict__ hstart,
                                               float* __restrict__ out) {
  const int lane = threadIdx.x & 63;
  const int w    = threadIdx.x >> 6;
  const int d    = blockIdx.x * 64 + w * 16 + (lane & 15);
  const int ng   = lane >> 4;
  const int c    = blockIdx.y;
  __shared__ __align__(16) float sB[CL][DS];
  __shared__ __align__(16) float sC[CL][DS];
  for (int i = threadIdx.x; i < CL * DS; i += 256) {
    int t = i >> 4, n = i & 15;
    sB[t][n] = xdbl[(size_t)(c * CL + t) * NE + DR + n];
    sC[t][n] = xdbl[(size_t)(c * CL + t) * NE + DR + DS + n];
  }
  __syncthreads();
  float4 av = *(const float4*)&A_log[(size_t)d * DS + ng * 4];
  float a[4] = {-__expf(av.x), -__expf(av.y), -__expf(av.z), -__expf(av.w)};
  float h[4];
#pragma unroll
  for (int j = 0; j < 4; ++j)
    h[j] = hstart[(size_t)(c * DS + ng * 4 + j) * DI + d];
  const float Dv = Dvec[d];

  const float* dp = &delta[(size_t)(c * CL) * DI + d];
  const float* xp = &x[(size_t)(c * CL) * DI + d];
  float* op = &out[(size_t)(c * CL) * DI + d];
  float dl = dp[0], xv = xp[0];
#pragma unroll 4
  for (int tt = 0; tt < CL; ++tt) {
    float dl_n = 0.f, xv_n = 0.f;
    if (tt + 1 < CL) { dl_n = dp[(size_t)(tt + 1) * DI]; xv_n = xp[(size_t)(tt + 1) * DI]; }
    float du = dl * xv;
    float4 b4 = *(const float4*)&sB[tt][ng * 4];
    float4 c4 = *(const float4*)&sC[tt][ng * 4];
    float bb[4] = {b4.x, b4.y, b4.z, b4.w};
    float cc[4] = {c4.x, c4.y, c4.z, c4.w};
    float y = 0.f;
#pragma unroll
    for (int j = 0; j < 4; ++j) {
      float dA = __expf(dl * a[j]);
      h[j] = dA * h[j] + du * bb[j];
      y += h[j] * cc[j];
    }
    y += __shfl_xor(y, 16, 64);
    y += __shfl_xor(y, 32, 64);
    if (ng == 0) op[(size_t)tt * DI] = fmaf(xv, Dv, y);
    dl = dl_n; xv = xv_n;
  }
}

extern "C" void kernel_launch(void* const* d_in, const int* in_sizes, int n_in,
                              void* d_out, int out_size, void* d_ws, size_t ws_size,
                              hipStream_t stream) {
  const float* x     = (const float*)d_in[0];
  const float* A_log = (const float*)d_in[1];
  const float* Dvec  = (const float*)d_in[2];
  const float* xw    = (const float*)d_in[3];
  const float* dtw   = (const float*)d_in[4];
  const float* dtb   = (const float*)d_in[5];
  float* out = (float*)d_out;

  char* ws = (char*)d_ws;
  float* part  = (float*)(ws + OFF_P);
  float* xdbl  = (float*)(ws + OFF_XDBL);
  float* delta = (float*)(ws + OFF_DELTA);
  float* hend  = (float*)(ws + OFF_HEND);
  float* aprod = (float*)(ws + OFF_APROD);
  unsigned short* wh = (unsigned short*)(ws + OFF_WH);
  unsigned short* wl = (unsigned short*)(ws + OFF_WL);
  unsigned short* xh = (unsigned short*)(ws + OFF_XH);
  unsigned short* xl = (unsigned short*)(ws + OFF_XL);

  k_cvt<<<800, 256, 0, stream>>>(dtw, wh, wl);
  k_xdbl_mfma<<<dim3(3, 32, SPLITK), 128, 0, stream>>>(x, xw, part);
  k_xdbl_reduce<<<192, 256, 0, stream>>>(part, xdbl, xh, xl);
  k_delta_mfma2<<<dim3(40, 16), 512, 0, stream>>>(xh, xl, wh, wl, dtb, delta);
  k_scan1<<<dim3(80, NC), 256, 0, stream>>>(x, delta, xdbl, A_log, hend, aprod);
  k_scan2<<<320, 256, 0, stream>>>(hend, aprod);
  k_scan3<<<dim3(80, NC), 256, 0, stream>>>(x, delta, xdbl, A_log, Dvec, hend, out);
}

// Round 9
// 107.193 us; speedup vs baseline: 1.7857x; 1.0617x over previous
//
#include <hip/hip_runtime.h>
#include <hip/hip_bf16.h>

#define L_SEQ 1024
#define DI    5120
#define DS    16
#define DR    160
#define NE    192      // DR + 2*DS
#define NC    16       // scan chunks
#define CL    64       // chunk length = L_SEQ/NC
#define SPLITK 16
#define KSPLIT (DI / SPLITK)   // 320
#define BK    64

// workspace layout (bytes); ws is ~256MiB (observed fill), we use ~70MB
#define OFF_P     0
#define SZ_P      (SPLITK * L_SEQ * NE * 4)   // 12,582,912
#define OFF_XDBL  (OFF_P + SZ_P)
#define SZ_XDBL   (L_SEQ * NE * 4)            // 786,432
#define OFF_DELTA (OFF_XDBL + SZ_XDBL)
#define SZ_DELTA  (L_SEQ * DI * 4)            // 20,971,520
#define OFF_HEND  (OFF_DELTA + SZ_DELTA)
#define SZ_H      (NC * DS * DI * 4)          // 5,242,880
#define OFF_APROD (OFF_HEND + SZ_H)
#define WS_END0   (OFF_APROD + SZ_H)
// dtw/xdbl bf16 hi/lo planes live inside HEND region (dead until k_scan1):
#define OFF_WH    OFF_HEND                     // dtw hi: 1,638,400
#define OFF_WL    (OFF_WH + 1638400)           // dtw lo
#define OFF_XH    (OFF_WL + 1638400)           // xdbl hi: 393,216
#define OFF_XL    (OFF_XH + 393216)            // xdbl lo (ends < OFF_APROD)
// x / xw planes: fresh space after aprod
#define OFF_XPH   WS_END0                      // x hi: 10,485,760
#define OFF_XPL   (OFF_XPH + 10485760)
#define OFF_XWH   (OFF_XPL + 10485760)         // xw hi: 1,966,080
#define OFF_XWL   (OFF_XWH + 1966080)          // total ~69.7 MB

typedef short s16x8 __attribute__((ext_vector_type(8)));   // 8 bf16 in 4 VGPRs
typedef float f32x4 __attribute__((ext_vector_type(4)));

__device__ __forceinline__ unsigned short bf_rn(float f) {
  unsigned u = __float_as_uint(f);
  u += 0x7FFFu + ((u >> 16) & 1u);      // round-to-nearest-even
  return (unsigned short)(u >> 16);
}
__device__ __forceinline__ void split_hilo(float f, unsigned short& h, unsigned short& l) {
  h = bf_rn(f);
  float hf = __uint_as_float(((unsigned)h) << 16);
  l = bf_rn(f - hf);
}

// ---------------- generic cvt: f32 -> bf16 hi/lo planes, 4 elems/thread
__global__ __launch_bounds__(256) void k_cvt(const float* __restrict__ src,
                                             unsigned short* __restrict__ hi,
                                             unsigned short* __restrict__ lo,
                                             int n4) {
  int i = blockIdx.x * 256 + threadIdx.x;
  if (i >= n4) return;
  int i4 = i * 4;
  float4 v = *(const float4*)&src[i4];
  float f[4] = {v.x, v.y, v.z, v.w};
  ushort4 h, l;
  unsigned short hh, ll;
  split_hilo(f[0], hh, ll); h.x = hh; l.x = ll;
  split_hilo(f[1], hh, ll); h.y = hh; l.y = ll;
  split_hilo(f[2], hh, ll); h.z = hh; l.z = ll;
  split_hilo(f[3], hh, ll); h.w = hh; l.w = ll;
  *(ushort4*)&hi[i4] = h;
  *(ushort4*)&lo[i4] = l;
}

// ---------------- GEMM1 (MFMA, preconverted planes): part[z][l][e] = x[l,:]·xw[e,:]
// block 256 = 4 waves (2l x 2e); tile 64l x 64e; K-chunk 320, staged BK=64
#define AST2 72   // LDS row stride in shorts (144B -> 2-way bank aliasing, free)
__global__ __launch_bounds__(256) void k_xdbl_mfma2(const unsigned short* __restrict__ xph,
                                                    const unsigned short* __restrict__ xpl,
                                                    const unsigned short* __restrict__ wxh,
                                                    const unsigned short* __restrict__ wxl,
                                                    float* __restrict__ part) {
  __shared__ unsigned short sAh[64 * AST2];
  __shared__ unsigned short sAl[64 * AST2];
  const int tid  = threadIdx.x;
  const int lane = tid & 63;
  const int w    = tid >> 6;            // 0..3
  const int wl_  = w >> 1;              // l-subtile 0..1
  const int we   = w & 1;               // e-subtile 0..1
  const int l0   = blockIdx.y * 64;
  const int e0   = blockIdx.x * 64 + we * 32;
  const int kb   = blockIdx.z * KSPLIT;
  const int rc   = lane & 15;
  const int kg   = (lane >> 4) * 8;

  f32x4 acc[2][2] = {};
  for (int k0 = 0; k0 < KSPLIT; k0 += BK) {
    __syncthreads();
    for (int idx = tid; idx < 64 * 8; idx += 256) {      // 64 rows x 8 chunks(8sh)
      int r = idx >> 3, c8 = (idx & 7) * 8;
      *(s16x8*)&sAh[r * AST2 + c8] = *(const s16x8*)&xph[(size_t)(l0 + r) * DI + kb + k0 + c8];
      *(s16x8*)&sAl[r * AST2 + c8] = *(const s16x8*)&xpl[(size_t)(l0 + r) * DI + kb + k0 + c8];
    }
    __syncthreads();
#pragma unroll
    for (int ks = 0; ks < BK; ks += 32) {
      s16x8 ah[2], al[2], bh[2], bl[2];
#pragma unroll
      for (int mf = 0; mf < 2; ++mf) {
        int row = wl_ * 32 + mf * 16 + rc;
        ah[mf] = *(const s16x8*)&sAh[row * AST2 + ks + kg];
        al[mf] = *(const s16x8*)&sAl[row * AST2 + ks + kg];
      }
#pragma unroll
      for (int nf = 0; nf < 2; ++nf) {
        size_t e = e0 + nf * 16 + rc;
        bh[nf] = *(const s16x8*)&wxh[e * DI + kb + k0 + ks + kg];
        bl[nf] = *(const s16x8*)&wxl[e * DI + kb + k0 + ks + kg];
      }
#pragma unroll
      for (int mf = 0; mf < 2; ++mf)
#pragma unroll
        for (int nf = 0; nf < 2; ++nf) {
          acc[mf][nf] = __builtin_amdgcn_mfma_f32_16x16x32_bf16(ah[mf], bh[nf], acc[mf][nf], 0, 0, 0);
          acc[mf][nf] = __builtin_amdgcn_mfma_f32_16x16x32_bf16(ah[mf], bl[nf], acc[mf][nf], 0, 0, 0);
          acc[mf][nf] = __builtin_amdgcn_mfma_f32_16x16x32_bf16(al[mf], bh[nf], acc[mf][nf], 0, 0, 0);
        }
    }
  }
#pragma unroll
  for (int mf = 0; mf < 2; ++mf)
#pragma unroll
    for (int nf = 0; nf < 2; ++nf)
#pragma unroll
      for (int r = 0; r < 4; ++r) {
        int l = l0 + wl_ * 32 + mf * 16 + (lane >> 4) * 4 + r;  // C/D: row=(lane>>4)*4+reg
        int e = e0 + nf * 16 + rc;                              //      col=lane&15
        part[((size_t)blockIdx.z * L_SEQ + l) * NE + e] = acc[mf][nf][r];
      }
}

// ---------------- reduce split-K partials; also emit xdbl bf16 hi/lo planes
__global__ __launch_bounds__(256) void k_xdbl_reduce(const float* __restrict__ part,
                                                     float* __restrict__ xdbl,
                                                     unsigned short* __restrict__ xh,
                                                     unsigned short* __restrict__ xl) {
  int i4 = (blockIdx.x * 256 + threadIdx.x) * 4;   // grid=192
  float4 s = {0.f, 0.f, 0.f, 0.f};
#pragma unroll
  for (int z = 0; z < SPLITK; ++z) {
    float4 p = *(const float4*)&part[(size_t)z * L_SEQ * NE + i4];
    s.x += p.x; s.y += p.y; s.z += p.z; s.w += p.w;
  }
  *(float4*)&xdbl[i4] = s;
  float f[4] = {s.x, s.y, s.z, s.w};
  ushort4 h, l;
  unsigned short hh, ll;
  split_hilo(f[0], hh, ll); h.x = hh; l.x = ll;
  split_hilo(f[1], hh, ll); h.y = hh; l.y = ll;
  split_hilo(f[2], hh, ll); h.z = hh; l.z = ll;
  split_hilo(f[3], hh, ll); h.w = hh; l.w = ll;
  *(ushort4*)&xh[i4] = h;
  *(ushort4*)&xl[i4] = l;
}

// ---------------- GEMM2 (MFMA, preconverted bf16): delta = softplus(dt·dtw^T + b)
#define AST 168
__global__ __launch_bounds__(512) void k_delta_mfma2(const unsigned short* __restrict__ xh,
                                                     const unsigned short* __restrict__ xl,
                                                     const unsigned short* __restrict__ wh,
                                                     const unsigned short* __restrict__ wlo,
                                                     const float* __restrict__ dtb,
                                                     float* __restrict__ delta) {
  __shared__ unsigned short sAh[64 * AST];
  __shared__ unsigned short sAl[64 * AST];
  const int tid  = threadIdx.x;
  const int lane = tid & 63;
  const int w    = tid >> 6;
  const int wl_  = w >> 2;
  const int wd   = w & 3;
  const int l0   = blockIdx.y * 64;
  const int d0   = blockIdx.x * 128 + wd * 32;
  const int rc   = lane & 15;
  const int kg   = (lane >> 4) * 8;

  for (int idx = tid; idx < 64 * 20; idx += 512) {
    int r = idx / 20, c8 = (idx % 20) * 8;
    *(s16x8*)&sAh[r * AST + c8] = *(const s16x8*)&xh[(size_t)(l0 + r) * NE + c8];
    *(s16x8*)&sAl[r * AST + c8] = *(const s16x8*)&xl[(size_t)(l0 + r) * NE + c8];
  }
  __syncthreads();

  f32x4 acc[2][2] = {};
#pragma unroll
  for (int k0 = 0; k0 < DR; k0 += 32) {
    s16x8 ah[2], al[2], bh[2], bl[2];
#pragma unroll
    for (int mf = 0; mf < 2; ++mf) {
      int row = wl_ * 32 + mf * 16 + rc;
      ah[mf] = *(const s16x8*)&sAh[row * AST + k0 + kg];
      al[mf] = *(const s16x8*)&sAl[row * AST + k0 + kg];
    }
#pragma unroll
    for (int nf = 0; nf < 2; ++nf) {
      size_t d = d0 + nf * 16 + rc;
      bh[nf] = *(const s16x8*)&wh[d * DR + k0 + kg];
      bl[nf] = *(const s16x8*)&wlo[d * DR + k0 + kg];
    }
#pragma unroll
    for (int mf = 0; mf < 2; ++mf)
#pragma unroll
      for (int nf = 0; nf < 2; ++nf) {
        acc[mf][nf] = __builtin_amdgcn_mfma_f32_16x16x32_bf16(ah[mf], bh[nf], acc[mf][nf], 0, 0, 0);
        acc[mf][nf] = __builtin_amdgcn_mfma_f32_16x16x32_bf16(ah[mf], bl[nf], acc[mf][nf], 0, 0, 0);
        acc[mf][nf] = __builtin_amdgcn_mfma_f32_16x16x32_bf16(al[mf], bh[nf], acc[mf][nf], 0, 0, 0);
      }
  }
#pragma unroll
  for (int nf = 0; nf < 2; ++nf) {
    int d = d0 + nf * 16 + rc;
    float bias = dtb[d];
#pragma unroll
    for (int mf = 0; mf < 2; ++mf)
#pragma unroll
      for (int r = 0; r < 4; ++r) {
        int l = l0 + wl_ * 32 + mf * 16 + (lane >> 4) * 4 + r;
        float z = acc[mf][nf][r] + bias;
        float sp = fmaxf(z, 0.f) + __logf(1.f + __expf(-fabsf(z)));
        delta[(size_t)l * DI + d] = sp;
      }
  }
}

// ---------------- scan pass 1 (4-way n-split, PF=8 prefetch)
__global__ __launch_bounds__(256) void k_scan1(const float* __restrict__ x,
                                               const float* __restrict__ delta,
                                               const float* __restrict__ xdbl,
                                               const float* __restrict__ A_log,
                                               float* __restrict__ hend,
                                               float* __restrict__ aprod) {
  const int lane = threadIdx.x & 63;
  const int w    = threadIdx.x >> 6;
  const int d    = blockIdx.x * 64 + w * 16 + (lane & 15);
  const int ng   = lane >> 4;
  const int c    = blockIdx.y;
  __shared__ __align__(16) float sB[CL][DS];
  for (int i = threadIdx.x; i < CL * DS; i += 256) {
    int t = i >> 4, n = i & 15;
    sB[t][n] = xdbl[(size_t)(c * CL + t) * NE + DR + n];
  }
  __syncthreads();
  float4 av = *(const float4*)&A_log[(size_t)d * DS + ng * 4];
  float a[4] = {-__expf(av.x), -__expf(av.y), -__expf(av.z), -__expf(av.w)};
  float h[4] = {0.f, 0.f, 0.f, 0.f};
  float sdl = 0.f;

  const float* dp = &delta[(size_t)(c * CL) * DI + d];
  const float* xp = &x[(size_t)(c * CL) * DI + d];
  float dlb[8], xvb[8];
#pragma unroll
  for (int j = 0; j < 8; ++j) { dlb[j] = dp[(size_t)j * DI]; xvb[j] = xp[(size_t)j * DI]; }
  for (int tt = 0; tt < CL; tt += 8) {
#pragma unroll
    for (int j = 0; j < 8; ++j) {
      float dl = dlb[j], xv = xvb[j];
      int tn = tt + 8 + j;
      if (tn < CL) { dlb[j] = dp[(size_t)tn * DI]; xvb[j] = xp[(size_t)tn * DI]; }
      float du = dl * xv;
      sdl += dl;
      float4 b4 = *(const float4*)&sB[tt + j][ng * 4];
      float bb[4] = {b4.x, b4.y, b4.z, b4.w};
#pragma unroll
      for (int q = 0; q < 4; ++q) {
        float dA = __expf(dl * a[q]);
        h[q] = dA * h[q] + du * bb[q];
      }
    }
  }
#pragma unroll
  for (int q = 0; q < 4; ++q) {
    int n = ng * 4 + q;
    hend[(size_t)(c * DS + n) * DI + d] = h[q];
    aprod[(size_t)(c * DS + n) * DI + d] = __expf(a[q] * sdl);
  }
}

// ---------------- scan pass 2: load-all-then-carry (in-place -> hstart)
__global__ __launch_bounds__(256) void k_scan2(float* __restrict__ hend,
                                               const float* __restrict__ aprod) {
  int i = blockIdx.x * 256 + threadIdx.x;   // 81920 total, grid=320
  float ap[NC], hv[NC];
#pragma unroll
  for (int c = 0; c < NC; ++c) {
    size_t idx = (size_t)c * DS * DI + i;
    ap[c] = aprod[idx];
    hv[c] = hend[idx];
  }
  float carry = 0.f;
#pragma unroll
  for (int c = 0; c < NC; ++c) {
    size_t idx = (size_t)c * DS * DI + i;
    hend[idx] = carry;
    carry = ap[c] * carry + hv[c];
  }
}

// ---------------- scan pass 3 (4-way n-split, PF=8): replay, emit y (f32)
__global__ __launch_bounds__(256) void k_scan3(const float* __restrict__ x,
                                               const float* __restrict__ delta,
                                               const float* __restrict__ xdbl,
                                               const float* __restrict__ A_log,
                                               const float* __restrict__ Dvec,
                                               const float* __restrict__ hstart,
                                               float* __restrict__ out) {
  const int lane = threadIdx.x & 63;
  const int w    = threadIdx.x >> 6;
  const int d    = blockIdx.x * 64 + w * 16 + (lane & 15);
  const int ng   = lane >> 4;
  const int c    = blockIdx.y;
  __shared__ __align__(16) float sB[CL][DS];
  __shared__ __align__(16) float sC[CL][DS];
  for (int i = threadIdx.x; i < CL * DS; i += 256) {
    int t = i >> 4, n = i & 15;
    sB[t][n] = xdbl[(size_t)(c * CL + t) * NE + DR + n];
    sC[t][n] = xdbl[(size_t)(c * CL + t) * NE + DR + DS + n];
  }
  __syncthreads();
  float4 av = *(const float4*)&A_log[(size_t)d * DS + ng * 4];
  float a[4] = {-__expf(av.x), -__expf(av.y), -__expf(av.z), -__expf(av.w)};
  float h[4];
#pragma unroll
  for (int q = 0; q < 4; ++q)
    h[q] = hstart[(size_t)(c * DS + ng * 4 + q) * DI + d];
  const float Dv = Dvec[d];

  const float* dp = &delta[(size_t)(c * CL) * DI + d];
  const float* xp = &x[(size_t)(c * CL) * DI + d];
  float* op = &out[(size_t)(c * CL) * DI + d];
  float dlb[8], xvb[8];
#pragma unroll
  for (int j = 0; j < 8; ++j) { dlb[j] = dp[(size_t)j * DI]; xvb[j] = xp[(size_t)j * DI]; }
  for (int tt = 0; tt < CL; tt += 8) {
#pragma unroll
    for (int j = 0; j < 8; ++j) {
      float dl = dlb[j], xv = xvb[j];
      int tn = tt + 8 + j;
      if (tn < CL) { dlb[j] = dp[(size_t)tn * DI]; xvb[j] = xp[(size_t)tn * DI]; }
      float du = dl * xv;
      float4 b4 = *(const float4*)&sB[tt + j][ng * 4];
      float4 c4 = *(const float4*)&sC[tt + j][ng * 4];
      float bb[4] = {b4.x, b4.y, b4.z, b4.w};
      float cc[4] = {c4.x, c4.y, c4.z, c4.w};
      float y = 0.f;
#pragma unroll
      for (int q = 0; q < 4; ++q) {
        float dA = __expf(dl * a[q]);
        h[q] = dA * h[q] + du * bb[q];
        y += h[q] * cc[q];
      }
      y += __shfl_xor(y, 16, 64);
      y += __shfl_xor(y, 32, 64);
      if (ng == 0) op[(size_t)(tt + j) * DI] = fmaf(xv, Dv, y);
    }
  }
}

extern "C" void kernel_launch(void* const* d_in, const int* in_sizes, int n_in,
                              void* d_out, int out_size, void* d_ws, size_t ws_size,
                              hipStream_t stream) {
  const float* x     = (const float*)d_in[0];
  const float* A_log = (const float*)d_in[1];
  const float* Dvec  = (const float*)d_in[2];
  const float* xw    = (const float*)d_in[3];
  const float* dtw   = (const float*)d_in[4];
  const float* dtb   = (const float*)d_in[5];
  float* out = (float*)d_out;

  char* ws = (char*)d_ws;
  float* part  = (float*)(ws + OFF_P);
  float* xdbl  = (float*)(ws + OFF_XDBL);
  float* delta = (float*)(ws + OFF_DELTA);
  float* hend  = (float*)(ws + OFF_HEND);
  float* aprod = (float*)(ws + OFF_APROD);
  unsigned short* wh  = (unsigned short*)(ws + OFF_WH);
  unsigned short* wl  = (unsigned short*)(ws + OFF_WL);
  unsigned short* xh  = (unsigned short*)(ws + OFF_XH);
  unsigned short* xl  = (unsigned short*)(ws + OFF_XL);
  unsigned short* xph = (unsigned short*)(ws + OFF_XPH);
  unsigned short* xpl = (unsigned short*)(ws + OFF_XPL);
  unsigned short* wxh = (unsigned short*)(ws + OFF_XWH);
  unsigned short* wxl = (unsigned short*)(ws + OFF_XWL);

  k_cvt<<<5120, 256, 0, stream>>>(x, xph, xpl, L_SEQ * DI / 4);      // x planes
  k_cvt<<<960, 256, 0, stream>>>(xw, wxh, wxl, NE * DI / 4);         // xw planes
  k_cvt<<<800, 256, 0, stream>>>(dtw, wh, wl, DI * DR / 4);          // dtw planes
  k_xdbl_mfma2<<<dim3(3, 16, SPLITK), 256, 0, stream>>>(xph, xpl, wxh, wxl, part);
  k_xdbl_reduce<<<192, 256, 0, stream>>>(part, xdbl, xh, xl);
  k_delta_mfma2<<<dim3(40, 16), 512, 0, stream>>>(xh, xl, wh, wl, dtb, delta);
  k_scan1<<<dim3(80, NC), 256, 0, stream>>>(x, delta, xdbl, A_log, hend, aprod);
  k_scan2<<<320, 256, 0, stream>>>(hend, aprod);
  k_scan3<<<dim3(80, NC), 256, 0, stream>>>(x, delta, xdbl, A_log, Dvec, hend, out);
}